// Round 1
// baseline (552.915 us; speedup 1.0000x reference)
//
#include <hip/hip_runtime.h>

// GCNConv forward: out = scatter_col( dis[row]*dis[col] * (x@W)[row] ) + dis^2*(x@W) + b
// deg over targets includes self loop -> deg >= 1 always.

#define D 64

__global__ __launch_bounds__(256) void deg_init_kernel(float* __restrict__ deg, int n) {
    int i = blockIdx.x * 256 + threadIdx.x;
    if (i < n) deg[i] = 1.0f;  // self-loop contributes 1
}

__global__ __launch_bounds__(256) void deg_count_kernel(const int* __restrict__ col, float* __restrict__ deg, int e) {
    int i = blockIdx.x * 256 + threadIdx.x;
    if (i < e) atomicAdd(&deg[col[i]], 1.0f);
}

__global__ __launch_bounds__(256) void deg_rsqrt_kernel(float* __restrict__ deg, int n) {
    int i = blockIdx.x * 256 + threadIdx.x;
    if (i < n) deg[i] = rsqrtf(deg[i]);  // deg >= 1, no zero case
}

// xw = x @ W   (one wave per row; W staged in LDS)
__global__ __launch_bounds__(256) void xw_kernel(const float* __restrict__ x, const float* __restrict__ W,
                                                 float* __restrict__ xw, int n) {
    __shared__ float Wl[D * D];
    int t = threadIdx.x;
    for (int i = t; i < D * D; i += 256) Wl[i] = W[i];
    __syncthreads();
    int lane = t & 63;
    int sub  = t >> 6;                    // 4 rows per block
    int row  = blockIdx.x * 4 + sub;
    if (row >= n) return;
    float xv = x[(size_t)row * D + lane]; // lane holds x[row][lane]
    float acc = 0.0f;
#pragma unroll
    for (int k = 0; k < D; ++k) {
        float xk = __shfl(xv, k);         // broadcast x[row][k] across the wave
        acc += xk * Wl[k * D + lane];
    }
    xw[(size_t)row * D + lane] = acc;
}

// out = b + dis^2 * xw   (self-loop term; also initializes out deterministically)
__global__ __launch_bounds__(256) void out_init_kernel(const float* __restrict__ xw, const float* __restrict__ dis,
                                                       const float* __restrict__ b, float* __restrict__ out, int n) {
    int i = blockIdx.x * 256 + threadIdx.x;
    if (i < n * D) {
        int node = i >> 6;
        int j = i & 63;
        float d = dis[node];
        out[i] = b[j] + d * d * xw[i];
    }
}

// one wave per edge: out[col] += dis[row]*dis[col]*xw[row]
__global__ __launch_bounds__(256) void scatter_kernel(const int* __restrict__ row, const int* __restrict__ col,
                                                      const float* __restrict__ dis, const float* __restrict__ xw,
                                                      float* __restrict__ out, int e) {
    int idx  = blockIdx.x * 4 + (threadIdx.x >> 6);
    int lane = threadIdx.x & 63;
    if (idx >= e) return;
    int r = row[idx];
    int c = col[idx];
    float w = dis[r] * dis[c];
    atomicAdd(&out[(size_t)c * D + lane], w * xw[(size_t)r * D + lane]);
}

extern "C" void kernel_launch(void* const* d_in, const int* in_sizes, int n_in,
                              void* d_out, int out_size, void* d_ws, size_t ws_size,
                              hipStream_t stream) {
    const float* x  = (const float*)d_in[0];
    const int*   ei = (const int*)d_in[1];
    const float* W  = (const float*)d_in[2];
    const float* b  = (const float*)d_in[3];
    float*       out = (float*)d_out;

    int n = in_sizes[0] / D;   // 100000
    int e = in_sizes[1] / 2;   // 1600000
    const int* row = ei;       // edge_index[0] = sources
    const int* col = ei + e;   // edge_index[1] = targets

    // ws layout: deg/dis [n floats, padded], xw [n*D floats]
    float* deg = (float*)d_ws;
    float* xw  = deg + (((size_t)n + 63) & ~(size_t)63);

    deg_init_kernel<<<(n + 255) / 256, 256, 0, stream>>>(deg, n);
    deg_count_kernel<<<(e + 255) / 256, 256, 0, stream>>>(col, deg, e);
    deg_rsqrt_kernel<<<(n + 255) / 256, 256, 0, stream>>>(deg, n);
    xw_kernel<<<(n + 3) / 4, 256, 0, stream>>>(x, W, xw, n);
    out_init_kernel<<<((size_t)n * D + 255) / 256, 256, 0, stream>>>(xw, deg, b, out, n);
    scatter_kernel<<<(e + 3) / 4, 256, 0, stream>>>(row, col, deg, xw, out, e);
}

// Round 2
// 366.887 us; speedup vs baseline: 1.5070x; 1.5070x over previous
//
#include <hip/hip_runtime.h>

// GCNConv forward via on-device CSR + register gather.
// t[i] = dis[i]*xw[i];  out[c] = b + dis[c]*( t[c] + sum_{edges r->c} t[r] )

#define D 64

// ======================= CSR-gather path =======================

__global__ __launch_bounds__(256) void cnt_init_kernel(int* __restrict__ cnt, int n) {
    int i = blockIdx.x * 256 + threadIdx.x;
    if (i < n) cnt[i] = 0;
}

__global__ __launch_bounds__(256) void hist_kernel(const int* __restrict__ col, int* __restrict__ cnt, int e) {
    int i = blockIdx.x * 256 + threadIdx.x;
    if (i < e) atomicAdd(&cnt[col[i]], 1);
}

// Block-wide exclusive scan of cnt -> off, block totals -> bsum. Also dis = rsqrt(cnt+1).
__global__ __launch_bounds__(1024) void scan1_kernel(const int* __restrict__ cnt, float* __restrict__ dis,
                                                     int* __restrict__ off, int* __restrict__ bsum, int n) {
    __shared__ int s[1024];
    int tid = threadIdx.x;
    int i = blockIdx.x * 1024 + tid;
    int v = (i < n) ? cnt[i] : 0;
    if (i < n) dis[i] = rsqrtf((float)(v + 1));  // +1 self loop, deg >= 1
    s[tid] = v;
    __syncthreads();
#pragma unroll
    for (int d = 1; d < 1024; d <<= 1) {
        int add = (tid >= d) ? s[tid - d] : 0;
        __syncthreads();
        s[tid] += add;
        __syncthreads();
    }
    int incl = s[tid];
    if (i < n) off[i] = incl - v;  // exclusive within block
    if (tid == 1023) bsum[blockIdx.x] = incl;
}

// Exclusive scan of block sums (nb <= 1024).
__global__ __launch_bounds__(1024) void scan2_kernel(int* __restrict__ bsum, int nb) {
    __shared__ int s[1024];
    int tid = threadIdx.x;
    int v = (tid < nb) ? bsum[tid] : 0;
    s[tid] = v;
    __syncthreads();
#pragma unroll
    for (int d = 1; d < 1024; d <<= 1) {
        int add = (tid >= d) ? s[tid - d] : 0;
        __syncthreads();
        s[tid] += add;
        __syncthreads();
    }
    if (tid < nb) bsum[tid] = s[tid] - v;  // exclusive
}

__global__ __launch_bounds__(1024) void scan3_kernel(int* __restrict__ off, const int* __restrict__ bsum,
                                                     int* __restrict__ cur, int n) {
    int i = blockIdx.x * 1024 + threadIdx.x;
    if (i < n) {
        int o = off[i] + bsum[blockIdx.x];
        off[i] = o;
        cur[i] = o;  // fill cursor starts at row offset; after fill, cur[c] == row end
    }
}

// t = dis * (x @ W)   (one wave per row; W staged in LDS)
__global__ __launch_bounds__(256) void xw_t_kernel(const float* __restrict__ x, const float* __restrict__ W,
                                                   const float* __restrict__ dis, float* __restrict__ t, int n) {
    __shared__ float Wl[D * D];
    int tid = threadIdx.x;
    for (int i = tid; i < D * D; i += 256) Wl[i] = W[i];
    __syncthreads();
    int lane = tid & 63;
    int row  = blockIdx.x * 4 + (tid >> 6);
    if (row >= n) return;
    float xv = x[(size_t)row * D + lane];
    float acc = 0.0f;
#pragma unroll
    for (int k = 0; k < D; ++k) {
        float xk = __shfl(xv, k);
        acc += xk * Wl[k * D + lane];
    }
    t[(size_t)row * D + lane] = dis[row] * acc;
}

// Ticket-fill CSR: srcs grouped by col.
__global__ __launch_bounds__(256) void fill_kernel(const int* __restrict__ row, const int* __restrict__ col,
                                                   int* __restrict__ cur, int* __restrict__ srcs, int e) {
    int i = blockIdx.x * 256 + threadIdx.x;
    if (i < e) {
        int pos = atomicAdd(&cur[col[i]], 1);
        srcs[pos] = row[i];
    }
}

// One wave per node: register-accumulate incoming t rows, single write.
__global__ __launch_bounds__(256) void gather_kernel(const int* __restrict__ off, const int* __restrict__ cur,
                                                     const int* __restrict__ srcs, const float* __restrict__ t,
                                                     const float* __restrict__ dis, const float* __restrict__ b,
                                                     float* __restrict__ out, int n) {
    int c    = blockIdx.x * 4 + (threadIdx.x >> 6);
    int lane = threadIdx.x & 63;
    if (c >= n) return;  // whole wave exits together
    int j0  = off[c];
    int jend = cur[c];  // == off[c] + cnt[c] after fill
    float acc = t[(size_t)c * D + lane];  // self-loop term (pre-scaled by dis[c] once more below)
    for (int jb = j0; jb < jend; jb += 64) {
        int m = jend - jb;
        if (m > 64) m = 64;
        int r = (jb + lane < jend) ? srcs[jb + lane] : 0;
        int k = 0;
        for (; k + 4 <= m; k += 4) {
            int r0 = __shfl(r, k), r1 = __shfl(r, k + 1), r2 = __shfl(r, k + 2), r3 = __shfl(r, k + 3);
            float v0 = t[(size_t)r0 * D + lane];
            float v1 = t[(size_t)r1 * D + lane];
            float v2 = t[(size_t)r2 * D + lane];
            float v3 = t[(size_t)r3 * D + lane];
            acc += v0; acc += v1; acc += v2; acc += v3;
        }
        for (; k < m; ++k) {
            int rk = __shfl(r, k);
            acc += t[(size_t)rk * D + lane];
        }
    }
    out[(size_t)c * D + lane] = b[lane] + dis[c] * acc;
}

// ======================= fallback: atomic-scatter path =======================

__global__ __launch_bounds__(256) void deg_init_kernel(float* __restrict__ deg, int n) {
    int i = blockIdx.x * 256 + threadIdx.x;
    if (i < n) deg[i] = 1.0f;
}
__global__ __launch_bounds__(256) void deg_count_kernel(const int* __restrict__ col, float* __restrict__ deg, int e) {
    int i = blockIdx.x * 256 + threadIdx.x;
    if (i < e) atomicAdd(&deg[col[i]], 1.0f);
}
__global__ __launch_bounds__(256) void deg_rsqrt_kernel(float* __restrict__ deg, int n) {
    int i = blockIdx.x * 256 + threadIdx.x;
    if (i < n) deg[i] = rsqrtf(deg[i]);
}
__global__ __launch_bounds__(256) void xw_kernel(const float* __restrict__ x, const float* __restrict__ W,
                                                 float* __restrict__ xw, int n) {
    __shared__ float Wl[D * D];
    int tid = threadIdx.x;
    for (int i = tid; i < D * D; i += 256) Wl[i] = W[i];
    __syncthreads();
    int lane = tid & 63;
    int row  = blockIdx.x * 4 + (tid >> 6);
    if (row >= n) return;
    float xv = x[(size_t)row * D + lane];
    float acc = 0.0f;
#pragma unroll
    for (int k = 0; k < D; ++k) acc += __shfl(xv, k) * Wl[k * D + lane];
    xw[(size_t)row * D + lane] = acc;
}
__global__ __launch_bounds__(256) void out_init_kernel(const float* __restrict__ xw, const float* __restrict__ dis,
                                                       const float* __restrict__ b, float* __restrict__ out, int n) {
    int i = blockIdx.x * 256 + threadIdx.x;
    if (i < n * D) {
        int node = i >> 6;
        float d = dis[node];
        out[i] = b[i & 63] + d * d * xw[i];
    }
}
__global__ __launch_bounds__(256) void scatter_kernel(const int* __restrict__ row, const int* __restrict__ col,
                                                      const float* __restrict__ dis, const float* __restrict__ xw,
                                                      float* __restrict__ out, int e) {
    int idx  = blockIdx.x * 4 + (threadIdx.x >> 6);
    int lane = threadIdx.x & 63;
    if (idx >= e) return;
    int r = row[idx], c = col[idx];
    float w = dis[r] * dis[c];
    atomicAdd(&out[(size_t)c * D + lane], w * xw[(size_t)r * D + lane]);
}

// ======================= launch =======================

extern "C" void kernel_launch(void* const* d_in, const int* in_sizes, int n_in,
                              void* d_out, int out_size, void* d_ws, size_t ws_size,
                              hipStream_t stream) {
    const float* x  = (const float*)d_in[0];
    const int*   ei = (const int*)d_in[1];
    const float* W  = (const float*)d_in[2];
    const float* b  = (const float*)d_in[3];
    float*       out = (float*)d_out;

    int n = in_sizes[0] / D;   // 100000
    int e = in_sizes[1] / 2;   // 1600000
    const int* row = ei;
    const int* col = ei + e;

    size_t nA = ((size_t)n + 255) & ~(size_t)255;  // aligned node count
    // layout: cnt[nA] off[nA] cur[nA] bsum[1024] (ints) | dis[nA] t[nA*D] (floats) | srcs[e] (ints)
    size_t needed = (3 * nA + 1024) * 4 + (nA + nA * D) * 4 + (size_t)e * 4;

    if (ws_size >= needed) {
        int*   cnt  = (int*)d_ws;
        int*   off  = cnt + nA;
        int*   cur  = off + nA;
        int*   bsum = cur + nA;
        float* dis  = (float*)(bsum + 1024);
        float* t    = dis + nA;
        int*   srcs = (int*)(t + nA * D);

        int nb = (n + 1023) / 1024;  // 98 <= 1024
        cnt_init_kernel<<<(n + 255) / 256, 256, 0, stream>>>(cnt, n);
        hist_kernel<<<(e + 255) / 256, 256, 0, stream>>>(col, cnt, e);
        scan1_kernel<<<nb, 1024, 0, stream>>>(cnt, dis, off, bsum, n);
        scan2_kernel<<<1, 1024, 0, stream>>>(bsum, nb);
        scan3_kernel<<<nb, 1024, 0, stream>>>(off, bsum, cur, n);
        xw_t_kernel<<<(n + 3) / 4, 256, 0, stream>>>(x, W, dis, t, n);
        fill_kernel<<<(e + 255) / 256, 256, 0, stream>>>(row, col, cur, srcs, e);
        gather_kernel<<<(n + 3) / 4, 256, 0, stream>>>(off, cur, srcs, t, dis, b, out, n);
    } else {
        float* deg = (float*)d_ws;
        float* xw  = deg + nA;
        deg_init_kernel<<<(n + 255) / 256, 256, 0, stream>>>(deg, n);
        deg_count_kernel<<<(e + 255) / 256, 256, 0, stream>>>(col, deg, e);
        deg_rsqrt_kernel<<<(n + 255) / 256, 256, 0, stream>>>(deg, n);
        xw_kernel<<<(n + 3) / 4, 256, 0, stream>>>(x, W, xw, n);
        out_init_kernel<<<((size_t)n * D + 255) / 256, 256, 0, stream>>>(xw, deg, b, out, n);
        scatter_kernel<<<(e + 3) / 4, 256, 0, stream>>>(row, col, deg, xw, out, e);
    }
}

// Round 3
// 241.129 us; speedup vs baseline: 2.2930x; 1.5215x over previous
//
#include <hip/hip_runtime.h>

// GCNConv forward via bucketed on-device CSR build + register gather.
// t[i] = dis[i]*(x@W)[i];  out[c] = b + dis[c]*( t[c] + sum_{edges r->c} t[r] )
//
// CSR build is a two-level counting sort on col:
//   bucket = col >> 7 (128 cols/bucket), NB <= 1024 buckets.
//   bhist -> bscan -> bscatter (bucket-grouped packed edges) -> bucket_build (per-col CSR).

#define D 64
#define BSH 7            // bucket shift: 128 cols per bucket
#define BCOLS 128
#define MAXNB 1024       // supports n <= 131072

// ---------- fast path: bucketed CSR build ----------

__global__ __launch_bounds__(256) void zinit_kernel(int* __restrict__ p, int m) {
    int i = blockIdx.x * 256 + threadIdx.x;
    if (i < m) p[i] = 0;
}

__global__ __launch_bounds__(256) void bhist_kernel(const int* __restrict__ col, int* __restrict__ bcnt,
                                                    int e, int nb) {
    __shared__ int h[MAXNB];
    int tid = threadIdx.x;
    for (int i = tid; i < nb; i += 256) h[i] = 0;
    __syncthreads();
    int stride = gridDim.x * 256;
    for (int i = blockIdx.x * 256 + tid; i < e; i += stride)
        atomicAdd(&h[col[i] >> BSH], 1);
    __syncthreads();
    for (int i = tid; i < nb; i += 256)
        if (h[i]) atomicAdd(&bcnt[i], h[i]);
}

// exclusive scan of bcnt (nb <= 1024) -> base, and init cur = base. base[nb] = e.
__global__ __launch_bounds__(1024) void bscan_kernel(const int* __restrict__ bcnt, int* __restrict__ base,
                                                     int* __restrict__ cur, int nb, int e) {
    __shared__ int s[1024];
    int tid = threadIdx.x;
    int v = (tid < nb) ? bcnt[tid] : 0;
    s[tid] = v;
    __syncthreads();
#pragma unroll
    for (int d = 1; d < 1024; d <<= 1) {
        int add = (tid >= d) ? s[tid - d] : 0;
        __syncthreads();
        s[tid] += add;
        __syncthreads();
    }
    if (tid < nb) { int ex = s[tid] - v; base[tid] = ex; cur[tid] = ex; }
    if (tid == 0) base[nb] = e;
}

// Bucket-grouped packed edges: binned[pos] = ((col&127) << 20) | row   (needs n <= 2^17)
__global__ __launch_bounds__(256) void bscatter_kernel(const int* __restrict__ row, const int* __restrict__ col,
                                                       int* __restrict__ bcur, unsigned int* __restrict__ binned,
                                                       int e, int nb, int chunk) {
    __shared__ int h[MAXNB];
    __shared__ int res[MAXNB];
    int tid = threadIdx.x;
    for (int i = tid; i < nb; i += 256) h[i] = 0;
    __syncthreads();
    int i0 = blockIdx.x * chunk;
    int i1 = i0 + chunk; if (i1 > e) i1 = e;
    for (int i = i0 + tid; i < i1; i += 256)
        atomicAdd(&h[col[i] >> BSH], 1);
    __syncthreads();
    for (int b = tid; b < nb; b += 256) {
        int c = h[b];
        res[b] = c ? atomicAdd(&bcur[b], c) : 0;
        h[b] = 0;  // reuse as local cursor
    }
    __syncthreads();
    for (int i = i0 + tid; i < i1; i += 256) {
        int cl = col[i];
        int b = cl >> BSH;
        int pos = res[b] + atomicAdd(&h[b], 1);
        binned[pos] = ((unsigned int)(cl & (BCOLS - 1)) << 20) | (unsigned int)row[i];
    }
}

// One block per bucket: per-col hist -> scan -> off/end/dis + srcs grouped by col.
__global__ __launch_bounds__(256) void bucket_build_kernel(const int* __restrict__ base,
                                                           const unsigned int* __restrict__ binned,
                                                           int* __restrict__ off, int* __restrict__ end,
                                                           float* __restrict__ dis, int* __restrict__ srcs,
                                                           int n) {
    __shared__ int hc[BCOLS];
    __shared__ int ho[BCOLS];
    __shared__ int hcur[BCOLS];
    int tid = threadIdx.x;
    int b = blockIdx.x;
    int s0 = base[b], s1 = base[b + 1];
    if (tid < BCOLS) hc[tid] = 0;
    __syncthreads();
    for (int i = s0 + tid; i < s1; i += 256)
        atomicAdd(&hc[binned[i] >> 20], 1);
    __syncthreads();
    if (tid < BCOLS) ho[tid] = hc[tid];
    __syncthreads();
#pragma unroll
    for (int d = 1; d < BCOLS; d <<= 1) {
        int add = (tid < BCOLS && tid >= d) ? ho[tid - d] : 0;
        __syncthreads();
        if (tid < BCOLS) ho[tid] += add;
        __syncthreads();
    }
    if (tid < BCOLS) {
        int col = (b << BSH) + tid;
        if (col < n) {
            int ex = ho[tid] - hc[tid];
            off[col] = s0 + ex;
            end[col] = s0 + ho[tid];
            dis[col] = rsqrtf((float)(hc[tid] + 1));  // +1 self loop
            hcur[tid] = s0 + ex;
        }
    }
    __syncthreads();
    for (int i = s0 + tid; i < s1; i += 256) {
        unsigned int v = binned[i];
        int lc = v >> 20;
        int pos = atomicAdd(&hcur[lc], 1);
        srcs[pos] = (int)(v & 0xFFFFFu);
    }
}

// ---------- shared: t = dis * (x @ W), register gather ----------

__global__ __launch_bounds__(256) void xw_t_kernel(const float* __restrict__ x, const float* __restrict__ W,
                                                   const float* __restrict__ dis, float* __restrict__ t, int n) {
    __shared__ float Wl[D * D];
    int tid = threadIdx.x;
    for (int i = tid; i < D * D; i += 256) Wl[i] = W[i];
    __syncthreads();
    int lane = tid & 63;
    int row  = blockIdx.x * 4 + (tid >> 6);
    if (row >= n) return;
    float xv = x[(size_t)row * D + lane];
    float acc = 0.0f;
#pragma unroll
    for (int k = 0; k < D; ++k) {
        float xk = __shfl(xv, k);
        acc += xk * Wl[k * D + lane];
    }
    t[(size_t)row * D + lane] = dis[row] * acc;
}

__global__ __launch_bounds__(256) void gather_kernel(const int* __restrict__ off, const int* __restrict__ end,
                                                     const int* __restrict__ srcs, const float* __restrict__ t,
                                                     const float* __restrict__ dis, const float* __restrict__ b,
                                                     float* __restrict__ out, int n) {
    int c    = blockIdx.x * 4 + (threadIdx.x >> 6);
    int lane = threadIdx.x & 63;
    if (c >= n) return;
    int j0 = off[c];
    int jend = end[c];
    float acc = t[(size_t)c * D + lane];  // self-loop term
    for (int jb = j0; jb < jend; jb += 64) {
        int m = jend - jb;
        if (m > 64) m = 64;
        int r = (jb + lane < jend) ? srcs[jb + lane] : 0;
        int k = 0;
        for (; k + 4 <= m; k += 4) {
            int r0 = __shfl(r, k), r1 = __shfl(r, k + 1), r2 = __shfl(r, k + 2), r3 = __shfl(r, k + 3);
            float v0 = t[(size_t)r0 * D + lane];
            float v1 = t[(size_t)r1 * D + lane];
            float v2 = t[(size_t)r2 * D + lane];
            float v3 = t[(size_t)r3 * D + lane];
            acc += v0; acc += v1; acc += v2; acc += v3;
        }
        for (; k < m; ++k) acc += t[(size_t)__shfl(r, k) * D + lane];
    }
    out[(size_t)c * D + lane] = b[lane] + dis[c] * acc;
}

// ---------- mid fallback: flat hist/scan/fill CSR (round-2 path) ----------

__global__ __launch_bounds__(256) void cnt_init_kernel(int* __restrict__ cnt, int n) {
    int i = blockIdx.x * 256 + threadIdx.x;
    if (i < n) cnt[i] = 0;
}
__global__ __launch_bounds__(256) void hist_kernel(const int* __restrict__ col, int* __restrict__ cnt, int e) {
    int i = blockIdx.x * 256 + threadIdx.x;
    if (i < e) atomicAdd(&cnt[col[i]], 1);
}
__global__ __launch_bounds__(1024) void scan1_kernel(const int* __restrict__ cnt, float* __restrict__ dis,
                                                     int* __restrict__ off, int* __restrict__ bsum, int n) {
    __shared__ int s[1024];
    int tid = threadIdx.x;
    int i = blockIdx.x * 1024 + tid;
    int v = (i < n) ? cnt[i] : 0;
    if (i < n) dis[i] = rsqrtf((float)(v + 1));
    s[tid] = v;
    __syncthreads();
#pragma unroll
    for (int d = 1; d < 1024; d <<= 1) {
        int add = (tid >= d) ? s[tid - d] : 0;
        __syncthreads();
        s[tid] += add;
        __syncthreads();
    }
    int incl = s[tid];
    if (i < n) off[i] = incl - v;
    if (tid == 1023) bsum[blockIdx.x] = incl;
}
__global__ __launch_bounds__(1024) void scan2_kernel(int* __restrict__ bsum, int nb) {
    __shared__ int s[1024];
    int tid = threadIdx.x;
    int v = (tid < nb) ? bsum[tid] : 0;
    s[tid] = v;
    __syncthreads();
#pragma unroll
    for (int d = 1; d < 1024; d <<= 1) {
        int add = (tid >= d) ? s[tid - d] : 0;
        __syncthreads();
        s[tid] += add;
        __syncthreads();
    }
    if (tid < nb) bsum[tid] = s[tid] - v;
}
__global__ __launch_bounds__(1024) void scan3_kernel(int* __restrict__ off, const int* __restrict__ bsum,
                                                     int* __restrict__ cur, int n) {
    int i = blockIdx.x * 1024 + threadIdx.x;
    if (i < n) {
        int o = off[i] + bsum[blockIdx.x];
        off[i] = o;
        cur[i] = o;
    }
}
__global__ __launch_bounds__(256) void fill_kernel(const int* __restrict__ row, const int* __restrict__ col,
                                                   int* __restrict__ cur, int* __restrict__ srcs, int e) {
    int i = blockIdx.x * 256 + threadIdx.x;
    if (i < e) {
        int pos = atomicAdd(&cur[col[i]], 1);
        srcs[pos] = row[i];
    }
}

// ---------- last fallback: atomic scatter ----------

__global__ __launch_bounds__(256) void deg_init_kernel(float* __restrict__ deg, int n) {
    int i = blockIdx.x * 256 + threadIdx.x;
    if (i < n) deg[i] = 1.0f;
}
__global__ __launch_bounds__(256) void deg_count_kernel(const int* __restrict__ col, float* __restrict__ deg, int e) {
    int i = blockIdx.x * 256 + threadIdx.x;
    if (i < e) atomicAdd(&deg[col[i]], 1.0f);
}
__global__ __launch_bounds__(256) void deg_rsqrt_kernel(float* __restrict__ deg, int n) {
    int i = blockIdx.x * 256 + threadIdx.x;
    if (i < n) deg[i] = rsqrtf(deg[i]);
}
__global__ __launch_bounds__(256) void out_init_kernel(const float* __restrict__ xw, const float* __restrict__ dis,
                                                       const float* __restrict__ b, float* __restrict__ out, int n) {
    int i = blockIdx.x * 256 + threadIdx.x;
    if (i < n * D) {
        int node = i >> 6;
        float d = dis[node];
        out[i] = b[i & 63] + d * d * xw[i];
    }
}
__global__ __launch_bounds__(256) void scatter_kernel(const int* __restrict__ row, const int* __restrict__ col,
                                                      const float* __restrict__ dis, const float* __restrict__ xw,
                                                      float* __restrict__ out, int e) {
    int idx  = blockIdx.x * 4 + (threadIdx.x >> 6);
    int lane = threadIdx.x & 63;
    if (idx >= e) return;
    int r = row[idx], c = col[idx];
    float w = dis[r] * dis[c];
    atomicAdd(&out[(size_t)c * D + lane], w * xw[(size_t)r * D + lane]);
}

// ---------- launch ----------

extern "C" void kernel_launch(void* const* d_in, const int* in_sizes, int n_in,
                              void* d_out, int out_size, void* d_ws, size_t ws_size,
                              hipStream_t stream) {
    const float* x  = (const float*)d_in[0];
    const int*   ei = (const int*)d_in[1];
    const float* W  = (const float*)d_in[2];
    const float* b  = (const float*)d_in[3];
    float*       out = (float*)d_out;

    int n = in_sizes[0] / D;   // 100000
    int e = in_sizes[1] / 2;   // 1600000
    const int* row = ei;
    const int* col = ei + e;

    size_t nA = ((size_t)n + 255) & ~(size_t)255;
    int nb = (n + BCOLS - 1) >> BSH;

    // fast-path layout: bcnt[1024] base[1056] bcur[1024] (ints) |
    //                   off[nA] end[nA] (ints) | dis[nA] t[nA*D] (floats) | binned[e] srcs[e]
    size_t fast_needed = (size_t)(1024 + 1056 + 1024) * 4 + (2 * nA) * 4 + (nA + nA * D) * 4 + 2 * (size_t)e * 4;
    size_t mid_needed  = (3 * nA + 1024) * 4 + (nA + nA * D) * 4 + (size_t)e * 4;

    if (n <= 131072 && nb <= MAXNB && ws_size >= fast_needed) {
        int*   bcnt   = (int*)d_ws;
        int*   base   = bcnt + 1024;
        int*   bcur   = base + 1056;
        int*   off    = bcur + 1024;
        int*   end    = off + nA;
        float* dis    = (float*)(end + nA);
        float* t      = dis + nA;
        unsigned int* binned = (unsigned int*)(t + nA * D);
        int*   srcs   = (int*)(binned + e);

        const int NBLK3 = 128;
        int chunk = (e + NBLK3 - 1) / NBLK3;

        zinit_kernel<<<(nb + 255) / 256, 256, 0, stream>>>(bcnt, nb);
        bhist_kernel<<<256, 256, 0, stream>>>(col, bcnt, e, nb);
        bscan_kernel<<<1, 1024, 0, stream>>>(bcnt, base, bcur, nb, e);
        bscatter_kernel<<<NBLK3, 256, 0, stream>>>(row, col, bcur, binned, e, nb, chunk);
        bucket_build_kernel<<<nb, 256, 0, stream>>>(base, binned, off, end, dis, srcs, n);
        xw_t_kernel<<<(n + 3) / 4, 256, 0, stream>>>(x, W, dis, t, n);
        gather_kernel<<<(n + 3) / 4, 256, 0, stream>>>(off, end, srcs, t, dis, b, out, n);
    } else if (ws_size >= mid_needed) {
        int*   cnt  = (int*)d_ws;
        int*   off  = cnt + nA;
        int*   cur  = off + nA;
        int*   bsum = cur + nA;
        float* dis  = (float*)(bsum + 1024);
        float* t    = dis + nA;
        int*   srcs = (int*)(t + nA * D);

        int nblk = (n + 1023) / 1024;
        cnt_init_kernel<<<(n + 255) / 256, 256, 0, stream>>>(cnt, n);
        hist_kernel<<<(e + 255) / 256, 256, 0, stream>>>(col, cnt, e);
        scan1_kernel<<<nblk, 1024, 0, stream>>>(cnt, dis, off, bsum, n);
        scan2_kernel<<<1, 1024, 0, stream>>>(bsum, nblk);
        scan3_kernel<<<nblk, 1024, 0, stream>>>(off, bsum, cur, n);
        xw_t_kernel<<<(n + 3) / 4, 256, 0, stream>>>(x, W, dis, t, n);
        fill_kernel<<<(e + 255) / 256, 256, 0, stream>>>(row, col, cur, srcs, e);
        gather_kernel<<<(n + 3) / 4, 256, 0, stream>>>(off, cur, srcs, t, dis, b, out, n);
    } else {
        float* deg = (float*)d_ws;
        float* xw  = deg + nA;
        deg_init_kernel<<<(n + 255) / 256, 256, 0, stream>>>(deg, n);
        deg_count_kernel<<<(e + 255) / 256, 256, 0, stream>>>(col, deg, e);
        deg_rsqrt_kernel<<<(n + 255) / 256, 256, 0, stream>>>(deg, n);
        xw_t_kernel<<<(n + 3) / 4, 256, 0, stream>>>(x, W, deg, xw, n);  // dis pre-applied? no:
        // note: xw_t multiplies by dis; emulate plain xw by passing deg=dis and compensating in scatter
        out_init_kernel<<<((size_t)n * D + 255) / 256, 256, 0, stream>>>(xw, deg, b, out, n);
        scatter_kernel<<<(e + 3) / 4, 256, 0, stream>>>(row, col, deg, xw, out, e);
    }
}

// Round 4
// 161.273 us; speedup vs baseline: 3.4284x; 1.4952x over previous
//
#include <hip/hip_runtime.h>

// GCNConv forward via bucketed on-device CSR build + register gather.
// t[i] = dis[i]*(x@W)[i];  out[c] = b + dis[c]*( t[c] + sum_{edges r->c} t[r] )

#define D 64
#define BSH 7            // bucket shift: 128 cols per bucket
#define BCOLS 128
#define MAXNB 1024       // supports n <= 131072
#define BM 128           // GEMM rows per block

// ---------- fast path: bucketed CSR build ----------

__global__ __launch_bounds__(256) void zinit_kernel(int* __restrict__ p, int m) {
    int i = blockIdx.x * 256 + threadIdx.x;
    if (i < m) p[i] = 0;
}

__global__ __launch_bounds__(256) void bhist_kernel(const int* __restrict__ col, int* __restrict__ bcnt,
                                                    int e, int nb) {
    __shared__ int h[MAXNB];
    int tid = threadIdx.x;
    for (int i = tid; i < nb; i += 256) h[i] = 0;
    __syncthreads();
    int stride = gridDim.x * 256;
    for (int i = blockIdx.x * 256 + tid; i < e; i += stride)
        atomicAdd(&h[col[i] >> BSH], 1);
    __syncthreads();
    for (int i = tid; i < nb; i += 256)
        if (h[i]) atomicAdd(&bcnt[i], h[i]);
}

__global__ __launch_bounds__(1024) void bscan_kernel(const int* __restrict__ bcnt, int* __restrict__ base,
                                                     int* __restrict__ cur, int nb, int e) {
    __shared__ int s[1024];
    int tid = threadIdx.x;
    int v = (tid < nb) ? bcnt[tid] : 0;
    s[tid] = v;
    __syncthreads();
#pragma unroll
    for (int d = 1; d < 1024; d <<= 1) {
        int add = (tid >= d) ? s[tid - d] : 0;
        __syncthreads();
        s[tid] += add;
        __syncthreads();
    }
    if (tid < nb) { int ex = s[tid] - v; base[tid] = ex; cur[tid] = ex; }
    if (tid == 0) base[nb] = e;
}

// Bucket-grouped packed edges: binned[pos] = ((col&127) << 20) | row   (needs n <= 2^17... row < 2^20)
__global__ __launch_bounds__(256) void bscatter_kernel(const int* __restrict__ row, const int* __restrict__ col,
                                                       int* __restrict__ bcur, unsigned int* __restrict__ binned,
                                                       int e, int nb, int chunk) {
    __shared__ int h[MAXNB];
    __shared__ int res[MAXNB];
    int tid = threadIdx.x;
    for (int i = tid; i < nb; i += 256) h[i] = 0;
    __syncthreads();
    int i0 = blockIdx.x * chunk;
    int i1 = i0 + chunk; if (i1 > e) i1 = e;
    for (int i = i0 + tid; i < i1; i += 256)
        atomicAdd(&h[col[i] >> BSH], 1);
    __syncthreads();
    for (int b = tid; b < nb; b += 256) {
        int c = h[b];
        res[b] = c ? atomicAdd(&bcur[b], c) : 0;
        h[b] = 0;  // reuse as local cursor
    }
    __syncthreads();
    for (int i = i0 + tid; i < i1; i += 256) {
        int cl = col[i];
        int b = cl >> BSH;
        int pos = res[b] + atomicAdd(&h[b], 1);
        binned[pos] = ((unsigned int)(cl & (BCOLS - 1)) << 20) | (unsigned int)row[i];
    }
}

__global__ __launch_bounds__(256) void bucket_build_kernel(const int* __restrict__ base,
                                                           const unsigned int* __restrict__ binned,
                                                           int* __restrict__ off, int* __restrict__ end,
                                                           float* __restrict__ dis, int* __restrict__ srcs,
                                                           int n) {
    __shared__ int hc[BCOLS];
    __shared__ int ho[BCOLS];
    __shared__ int hcur[BCOLS];
    int tid = threadIdx.x;
    int b = blockIdx.x;
    int s0 = base[b], s1 = base[b + 1];
    if (tid < BCOLS) hc[tid] = 0;
    __syncthreads();
    for (int i = s0 + tid; i < s1; i += 256)
        atomicAdd(&hc[binned[i] >> 20], 1);
    __syncthreads();
    if (tid < BCOLS) ho[tid] = hc[tid];
    __syncthreads();
#pragma unroll
    for (int d = 1; d < BCOLS; d <<= 1) {
        int add = (tid < BCOLS && tid >= d) ? ho[tid - d] : 0;
        __syncthreads();
        if (tid < BCOLS) ho[tid] += add;
        __syncthreads();
    }
    if (tid < BCOLS) {
        int col = (b << BSH) + tid;
        if (col < n) {
            int ex = ho[tid] - hc[tid];
            off[col] = s0 + ex;
            end[col] = s0 + ho[tid];
            dis[col] = rsqrtf((float)(hc[tid] + 1));  // +1 self loop
            hcur[tid] = s0 + ex;
        }
    }
    __syncthreads();
    for (int i = s0 + tid; i < s1; i += 256) {
        unsigned int v = binned[i];
        int lc = v >> 20;
        int pos = atomicAdd(&hcur[lc], 1);
        srcs[pos] = (int)(v & 0xFFFFFu);
    }
}

// ---------- t = dis * (x @ W): register-tiled fp32 GEMM ----------
// 256 threads own BM=128 rows x 64 cols; thread tile 8 rows x 4 cols.
// Per k-step per thread: 3 ds_read_b128 + 32 v_fma (vs 1 flop/LDS-op before).

__global__ __launch_bounds__(256) void xw_t_gemm_kernel(const float* __restrict__ x, const float* __restrict__ W,
                                                        const float* __restrict__ dis, float* __restrict__ t,
                                                        int n) {
    __shared__ float xT[D][BM];   // [k][row], 32 KB
    __shared__ float Wl[D][D];    // [k][col], 16 KB
    int tid = threadIdx.x;
    int r0 = blockIdx.x * BM;

    // stage W (linear copy, b128 writes)
    {
        const float4* Wv = (const float4*)W;
        float4* Wd = (float4*)&Wl[0][0];
#pragma unroll
        for (int j = 0; j < 4; ++j) Wd[j * 256 + tid] = Wv[j * 256 + tid];
    }
    // stage x transposed: thread -> row tid>>1, col-half (tid&1)*32
    {
        int row = tid >> 1;
        int c0 = (tid & 1) * 32;
        int gr = r0 + row;
        if (gr < n) {
            const float4* xv = (const float4*)(x + (size_t)gr * D + c0);
#pragma unroll
            for (int j = 0; j < 8; ++j) {
                float4 v = xv[j];
                int c = c0 + j * 4;
                xT[c + 0][row] = v.x;
                xT[c + 1][row] = v.y;
                xT[c + 2][row] = v.z;
                xT[c + 3][row] = v.w;
            }
        }
    }
    __syncthreads();

    int cg = tid & 15;   // cols cg*4 .. +3
    int rg = tid >> 4;   // rows rg*8 .. +7
    float acc[8][4];
#pragma unroll
    for (int i = 0; i < 8; ++i)
#pragma unroll
        for (int j = 0; j < 4; ++j) acc[i][j] = 0.0f;

#pragma unroll 8
    for (int k = 0; k < D; ++k) {
        float4 xa = *(const float4*)&xT[k][rg * 8];
        float4 xb = *(const float4*)&xT[k][rg * 8 + 4];
        float4 wv = *(const float4*)&Wl[k][cg * 4];
        float xr[8] = {xa.x, xa.y, xa.z, xa.w, xb.x, xb.y, xb.z, xb.w};
        float wr[4] = {wv.x, wv.y, wv.z, wv.w};
#pragma unroll
        for (int i = 0; i < 8; ++i)
#pragma unroll
            for (int j = 0; j < 4; ++j) acc[i][j] += xr[i] * wr[j];
    }

#pragma unroll
    for (int i = 0; i < 8; ++i) {
        int gr = r0 + rg * 8 + i;
        if (gr < n) {
            float dsc = dis[gr];
            float4 o;
            o.x = acc[i][0] * dsc; o.y = acc[i][1] * dsc;
            o.z = acc[i][2] * dsc; o.w = acc[i][3] * dsc;
            *(float4*)(t + (size_t)gr * D + cg * 4) = o;
        }
    }
}

// ---------- gather: one wave per node ----------

__global__ __launch_bounds__(256) void gather_kernel(const int* __restrict__ off, const int* __restrict__ end,
                                                     const int* __restrict__ srcs, const float* __restrict__ t,
                                                     const float* __restrict__ dis, const float* __restrict__ b,
                                                     float* __restrict__ out, int n) {
    int c    = blockIdx.x * 4 + (threadIdx.x >> 6);
    int lane = threadIdx.x & 63;
    if (c >= n) return;
    int j0 = off[c];
    int jend = end[c];
    float acc = t[(size_t)c * D + lane];  // self-loop term
    for (int jb = j0; jb < jend; jb += 64) {
        int m = jend - jb;
        if (m > 64) m = 64;
        int r = (jb + lane < jend) ? srcs[jb + lane] : 0;
        int k = 0;
        for (; k + 4 <= m; k += 4) {
            int r0 = __shfl(r, k), r1 = __shfl(r, k + 1), r2 = __shfl(r, k + 2), r3 = __shfl(r, k + 3);
            float v0 = t[(size_t)r0 * D + lane];
            float v1 = t[(size_t)r1 * D + lane];
            float v2 = t[(size_t)r2 * D + lane];
            float v3 = t[(size_t)r3 * D + lane];
            acc += v0; acc += v1; acc += v2; acc += v3;
        }
        for (; k < m; ++k) acc += t[(size_t)__shfl(r, k) * D + lane];
    }
    out[(size_t)c * D + lane] = b[lane] + dis[c] * acc;
}

// ---------- mid fallback: flat hist/scan/fill CSR ----------

__global__ __launch_bounds__(256) void cnt_init_kernel(int* __restrict__ cnt, int n) {
    int i = blockIdx.x * 256 + threadIdx.x;
    if (i < n) cnt[i] = 0;
}
__global__ __launch_bounds__(256) void hist_kernel(const int* __restrict__ col, int* __restrict__ cnt, int e) {
    int i = blockIdx.x * 256 + threadIdx.x;
    if (i < e) atomicAdd(&cnt[col[i]], 1);
}
__global__ __launch_bounds__(1024) void scan1_kernel(const int* __restrict__ cnt, float* __restrict__ dis,
                                                     int* __restrict__ off, int* __restrict__ bsum, int n) {
    __shared__ int s[1024];
    int tid = threadIdx.x;
    int i = blockIdx.x * 1024 + tid;
    int v = (i < n) ? cnt[i] : 0;
    if (i < n) dis[i] = rsqrtf((float)(v + 1));
    s[tid] = v;
    __syncthreads();
#pragma unroll
    for (int d = 1; d < 1024; d <<= 1) {
        int add = (tid >= d) ? s[tid - d] : 0;
        __syncthreads();
        s[tid] += add;
        __syncthreads();
    }
    int incl = s[tid];
    if (i < n) off[i] = incl - v;
    if (tid == 1023) bsum[blockIdx.x] = incl;
}
__global__ __launch_bounds__(1024) void scan2_kernel(int* __restrict__ bsum, int nb) {
    __shared__ int s[1024];
    int tid = threadIdx.x;
    int v = (tid < nb) ? bsum[tid] : 0;
    s[tid] = v;
    __syncthreads();
#pragma unroll
    for (int d = 1; d < 1024; d <<= 1) {
        int add = (tid >= d) ? s[tid - d] : 0;
        __syncthreads();
        s[tid] += add;
        __syncthreads();
    }
    if (tid < nb) bsum[tid] = s[tid] - v;
}
__global__ __launch_bounds__(1024) void scan3_kernel(int* __restrict__ off, const int* __restrict__ bsum,
                                                     int* __restrict__ cur, int n) {
    int i = blockIdx.x * 1024 + threadIdx.x;
    if (i < n) {
        int o = off[i] + bsum[blockIdx.x];
        off[i] = o;
        cur[i] = o;
    }
}
__global__ __launch_bounds__(256) void fill_kernel(const int* __restrict__ row, const int* __restrict__ col,
                                                   int* __restrict__ cur, int* __restrict__ srcs, int e) {
    int i = blockIdx.x * 256 + threadIdx.x;
    if (i < e) {
        int pos = atomicAdd(&cur[col[i]], 1);
        srcs[pos] = row[i];
    }
}

// ---------- last fallback: atomic scatter (fixed normalization) ----------

__global__ __launch_bounds__(256) void deg_init_kernel(float* __restrict__ deg, int n) {
    int i = blockIdx.x * 256 + threadIdx.x;
    if (i < n) deg[i] = 1.0f;
}
__global__ __launch_bounds__(256) void deg_count_kernel(const int* __restrict__ col, float* __restrict__ deg, int e) {
    int i = blockIdx.x * 256 + threadIdx.x;
    if (i < e) atomicAdd(&deg[col[i]], 1.0f);
}
__global__ __launch_bounds__(256) void deg_rsqrt_kernel(float* __restrict__ deg, int n) {
    int i = blockIdx.x * 256 + threadIdx.x;
    if (i < n) deg[i] = rsqrtf(deg[i]);
}
__global__ __launch_bounds__(256) void xw_kernel(const float* __restrict__ x, const float* __restrict__ W,
                                                 float* __restrict__ xw, int n) {
    __shared__ float Wl[D * D];
    int tid = threadIdx.x;
    for (int i = tid; i < D * D; i += 256) Wl[i] = W[i];
    __syncthreads();
    int lane = tid & 63;
    int row  = blockIdx.x * 4 + (tid >> 6);
    if (row >= n) return;
    float xv = x[(size_t)row * D + lane];
    float acc = 0.0f;
#pragma unroll
    for (int k = 0; k < D; ++k) acc += __shfl(xv, k) * Wl[k * D + lane];
    xw[(size_t)row * D + lane] = acc;
}
__global__ __launch_bounds__(256) void out_init_kernel(const float* __restrict__ xw, const float* __restrict__ dis,
                                                       const float* __restrict__ b, float* __restrict__ out, int n) {
    int i = blockIdx.x * 256 + threadIdx.x;
    if (i < n * D) {
        int node = i >> 6;
        float d = dis[node];
        out[i] = b[i & 63] + d * d * xw[i];
    }
}
__global__ __launch_bounds__(256) void scatter_kernel(const int* __restrict__ row, const int* __restrict__ col,
                                                      const float* __restrict__ dis, const float* __restrict__ xw,
                                                      float* __restrict__ out, int e) {
    int idx  = blockIdx.x * 4 + (threadIdx.x >> 6);
    int lane = threadIdx.x & 63;
    if (idx >= e) return;
    int r = row[idx], c = col[idx];
    float w = dis[r] * dis[c];
    atomicAdd(&out[(size_t)c * D + lane], w * xw[(size_t)r * D + lane]);
}

// ---------- launch ----------

extern "C" void kernel_launch(void* const* d_in, const int* in_sizes, int n_in,
                              void* d_out, int out_size, void* d_ws, size_t ws_size,
                              hipStream_t stream) {
    const float* x  = (const float*)d_in[0];
    const int*   ei = (const int*)d_in[1];
    const float* W  = (const float*)d_in[2];
    const float* b  = (const float*)d_in[3];
    float*       out = (float*)d_out;

    int n = in_sizes[0] / D;   // 100000
    int e = in_sizes[1] / 2;   // 1600000
    const int* row = ei;
    const int* col = ei + e;

    size_t nA = ((size_t)n + 255) & ~(size_t)255;
    int nb = (n + BCOLS - 1) >> BSH;

    size_t fast_needed = (size_t)(1024 + 1056 + 1024) * 4 + (2 * nA) * 4 + (nA + nA * D) * 4 + 2 * (size_t)e * 4;
    size_t mid_needed  = (3 * nA + 1024) * 4 + (nA + nA * D) * 4 + (size_t)e * 4;

    if (n <= 131072 && nb <= MAXNB && ws_size >= fast_needed) {
        int*   bcnt   = (int*)d_ws;
        int*   base   = bcnt + 1024;
        int*   bcur   = base + 1056;
        int*   off    = bcur + 1024;
        int*   end    = off + nA;
        float* dis    = (float*)(end + nA);
        float* t      = dis + nA;
        unsigned int* binned = (unsigned int*)(t + nA * D);
        int*   srcs   = (int*)(binned + e);

        const int NBLK3 = 128;
        int chunk = (e + NBLK3 - 1) / NBLK3;

        zinit_kernel<<<(nb + 255) / 256, 256, 0, stream>>>(bcnt, nb);
        bhist_kernel<<<256, 256, 0, stream>>>(col, bcnt, e, nb);
        bscan_kernel<<<1, 1024, 0, stream>>>(bcnt, base, bcur, nb, e);
        bscatter_kernel<<<NBLK3, 256, 0, stream>>>(row, col, bcur, binned, e, nb, chunk);
        bucket_build_kernel<<<nb, 256, 0, stream>>>(base, binned, off, end, dis, srcs, n);
        xw_t_gemm_kernel<<<(n + BM - 1) / BM, 256, 0, stream>>>(x, W, dis, t, n);
        gather_kernel<<<(n + 3) / 4, 256, 0, stream>>>(off, end, srcs, t, dis, b, out, n);
    } else if (ws_size >= mid_needed) {
        int*   cnt  = (int*)d_ws;
        int*   off  = cnt + nA;
        int*   cur  = off + nA;
        int*   bsum = cur + nA;
        float* dis  = (float*)(bsum + 1024);
        float* t    = dis + nA;
        int*   srcs = (int*)(t + nA * D);

        int nblk = (n + 1023) / 1024;
        cnt_init_kernel<<<(n + 255) / 256, 256, 0, stream>>>(cnt, n);
        hist_kernel<<<(e + 255) / 256, 256, 0, stream>>>(col, cnt, e);
        scan1_kernel<<<nblk, 1024, 0, stream>>>(cnt, dis, off, bsum, n);
        scan2_kernel<<<1, 1024, 0, stream>>>(bsum, nblk);
        scan3_kernel<<<nblk, 1024, 0, stream>>>(off, bsum, cur, n);
        xw_t_gemm_kernel<<<(n + BM - 1) / BM, 256, 0, stream>>>(x, W, dis, t, n);
        fill_kernel<<<(e + 255) / 256, 256, 0, stream>>>(row, col, cur, srcs, e);
        gather_kernel<<<(n + 3) / 4, 256, 0, stream>>>(off, cur, srcs, t, dis, b, out, n);
    } else {
        float* deg = (float*)d_ws;
        float* xw  = deg + nA;
        deg_init_kernel<<<(n + 255) / 256, 256, 0, stream>>>(deg, n);
        deg_count_kernel<<<(e + 255) / 256, 256, 0, stream>>>(col, deg, e);
        deg_rsqrt_kernel<<<(n + 255) / 256, 256, 0, stream>>>(deg, n);
        xw_kernel<<<(n + 3) / 4, 256, 0, stream>>>(x, W, xw, n);
        out_init_kernel<<<((size_t)n * D + 255) / 256, 256, 0, stream>>>(xw, deg, b, out, n);
        scatter_kernel<<<(e + 3) / 4, 256, 0, stream>>>(row, col, deg, xw, out, e);
    }
}

// Round 5
// 145.229 us; speedup vs baseline: 3.8072x; 1.1105x over previous
//
#include <hip/hip_runtime.h>

// GCNConv forward via bucketed on-device CSR build + float4 register gather.
// t[i] = dis[i]*(x@W)[i];  out[c] = b + dis[c]*( t[c] + sum_{edges r->c} t[r] )

#define D 64
#define BSH 7            // bucket shift: 128 cols per bucket
#define BCOLS 128
#define MAXNB 1024       // supports n <= 131072 (and row fits in 20 bits)
#define BM 128           // GEMM rows per block
#define NBLK3 512        // bscatter blocks (occupancy fix: was 128 -> 3.7% occ)

// ---------- fast path: bucketed CSR build ----------

__global__ __launch_bounds__(256) void zinit_kernel(int* __restrict__ p, int m) {
    int i = blockIdx.x * 256 + threadIdx.x;
    if (i < m) p[i] = 0;
}

__global__ __launch_bounds__(256) void bhist_kernel(const int* __restrict__ col, int* __restrict__ bcnt,
                                                    int e, int nb) {
    __shared__ int h[MAXNB];
    int tid = threadIdx.x;
    for (int i = tid; i < nb; i += 256) h[i] = 0;
    __syncthreads();
    int stride = gridDim.x * 256;
    for (int i = blockIdx.x * 256 + tid; i < e; i += stride)
        atomicAdd(&h[col[i] >> BSH], 1);
    __syncthreads();
    for (int i = tid; i < nb; i += 256)
        if (h[i]) atomicAdd(&bcnt[i], h[i]);
}

__global__ __launch_bounds__(1024) void bscan_kernel(const int* __restrict__ bcnt, int* __restrict__ base,
                                                     int* __restrict__ cur, int nb, int e) {
    __shared__ int s[1024];
    int tid = threadIdx.x;
    int v = (tid < nb) ? bcnt[tid] : 0;
    s[tid] = v;
    __syncthreads();
#pragma unroll
    for (int d = 1; d < 1024; d <<= 1) {
        int add = (tid >= d) ? s[tid - d] : 0;
        __syncthreads();
        s[tid] += add;
        __syncthreads();
    }
    if (tid < nb) { int ex = s[tid] - v; base[tid] = ex; cur[tid] = ex; }
    if (tid == 0) base[nb] = e;
}

// Bucket-grouped packed edges: binned[pos] = ((col&127) << 20) | row
__global__ __launch_bounds__(256) void bscatter_kernel(const int* __restrict__ row, const int* __restrict__ col,
                                                       int* __restrict__ bcur, unsigned int* __restrict__ binned,
                                                       int e, int nb, int chunk) {
    __shared__ int h[MAXNB];
    __shared__ int res[MAXNB];
    int tid = threadIdx.x;
    for (int i = tid; i < nb; i += 256) h[i] = 0;
    __syncthreads();
    int i0 = blockIdx.x * chunk;
    int i1 = i0 + chunk; if (i1 > e) i1 = e;
    for (int i = i0 + tid; i < i1; i += 256)
        atomicAdd(&h[col[i] >> BSH], 1);
    __syncthreads();
    for (int b = tid; b < nb; b += 256) {
        int c = h[b];
        res[b] = c ? atomicAdd(&bcur[b], c) : 0;
        h[b] = 0;  // reuse as local cursor
    }
    __syncthreads();
    for (int i = i0 + tid; i < i1; i += 256) {
        int cl = col[i];
        int b = cl >> BSH;
        int pos = res[b] + atomicAdd(&h[b], 1);
        binned[pos] = ((unsigned int)(cl & (BCOLS - 1)) << 20) | (unsigned int)row[i];
    }
}

__global__ __launch_bounds__(256) void bucket_build_kernel(const int* __restrict__ base,
                                                           const unsigned int* __restrict__ binned,
                                                           int* __restrict__ off, int* __restrict__ end,
                                                           float* __restrict__ dis, int* __restrict__ srcs,
                                                           int n) {
    __shared__ int hc[BCOLS];
    __shared__ int ho[BCOLS];
    __shared__ int hcur[BCOLS];
    int tid = threadIdx.x;
    int b = blockIdx.x;
    int s0 = base[b], s1 = base[b + 1];
    if (tid < BCOLS) hc[tid] = 0;
    __syncthreads();
    for (int i = s0 + tid; i < s1; i += 256)
        atomicAdd(&hc[binned[i] >> 20], 1);
    __syncthreads();
    if (tid < BCOLS) ho[tid] = hc[tid];
    __syncthreads();
#pragma unroll
    for (int d = 1; d < BCOLS; d <<= 1) {
        int add = (tid < BCOLS && tid >= d) ? ho[tid - d] : 0;
        __syncthreads();
        if (tid < BCOLS) ho[tid] += add;
        __syncthreads();
    }
    if (tid < BCOLS) {
        int col = (b << BSH) + tid;
        if (col < n) {
            int ex = ho[tid] - hc[tid];
            off[col] = s0 + ex;
            end[col] = s0 + ho[tid];
            dis[col] = rsqrtf((float)(hc[tid] + 1));  // +1 self loop
            hcur[tid] = s0 + ex;
        }
    }
    __syncthreads();
    for (int i = s0 + tid; i < s1; i += 256) {
        unsigned int v = binned[i];
        int lc = v >> 20;
        int pos = atomicAdd(&hcur[lc], 1);
        srcs[pos] = (int)(v & 0xFFFFFu);
    }
}

// ---------- t = dis * (x @ W): register-tiled fp32 GEMM ----------

__global__ __launch_bounds__(256) void xw_t_gemm_kernel(const float* __restrict__ x, const float* __restrict__ W,
                                                        const float* __restrict__ dis, float* __restrict__ t,
                                                        int n) {
    __shared__ float xT[D][BM];   // [k][row], 32 KB
    __shared__ float Wl[D][D];    // [k][col], 16 KB
    int tid = threadIdx.x;
    int r0 = blockIdx.x * BM;

    {
        const float4* Wv = (const float4*)W;
        float4* Wd = (float4*)&Wl[0][0];
#pragma unroll
        for (int j = 0; j < 4; ++j) Wd[j * 256 + tid] = Wv[j * 256 + tid];
    }
    {
        int row = tid >> 1;
        int c0 = (tid & 1) * 32;
        int gr = r0 + row;
        if (gr < n) {
            const float4* xv = (const float4*)(x + (size_t)gr * D + c0);
#pragma unroll
            for (int j = 0; j < 8; ++j) {
                float4 v = xv[j];
                int c = c0 + j * 4;
                xT[c + 0][row] = v.x;
                xT[c + 1][row] = v.y;
                xT[c + 2][row] = v.z;
                xT[c + 3][row] = v.w;
            }
        }
    }
    __syncthreads();

    int cg = tid & 15;
    int rg = tid >> 4;
    float acc[8][4];
#pragma unroll
    for (int i = 0; i < 8; ++i)
#pragma unroll
        for (int j = 0; j < 4; ++j) acc[i][j] = 0.0f;

#pragma unroll 8
    for (int k = 0; k < D; ++k) {
        float4 xa = *(const float4*)&xT[k][rg * 8];
        float4 xb = *(const float4*)&xT[k][rg * 8 + 4];
        float4 wv = *(const float4*)&Wl[k][cg * 4];
        float xr[8] = {xa.x, xa.y, xa.z, xa.w, xb.x, xb.y, xb.z, xb.w};
        float wr[4] = {wv.x, wv.y, wv.z, wv.w};
#pragma unroll
        for (int i = 0; i < 8; ++i)
#pragma unroll
            for (int j = 0; j < 4; ++j) acc[i][j] += xr[i] * wr[j];
    }

#pragma unroll
    for (int i = 0; i < 8; ++i) {
        int gr = r0 + rg * 8 + i;
        if (gr < n) {
            float dsc = dis[gr];
            float4 o;
            o.x = acc[i][0] * dsc; o.y = acc[i][1] * dsc;
            o.z = acc[i][2] * dsc; o.w = acc[i][3] * dsc;
            *(float4*)(t + (size_t)gr * D + cg * 4) = o;
        }
    }
}

// ---------- gather: one wave per node, float4 lanes (4 edges per load step) ----------
// lane = e4*16 + d16: subgroup e4 handles edge (k+e4), d16 covers 16 float4 chunks of the row.

__global__ __launch_bounds__(256) void gather4_kernel(const int* __restrict__ off, const int* __restrict__ end,
                                                      const int* __restrict__ srcs, const float* __restrict__ t,
                                                      const float* __restrict__ dis, const float* __restrict__ b,
                                                      float* __restrict__ out, int n) {
    int c    = blockIdx.x * 4 + (threadIdx.x >> 6);
    int lane = threadIdx.x & 63;
    if (c >= n) return;
    int e4  = lane >> 4;
    int d16 = lane & 15;
    int j0 = off[c];
    int jend = end[c];

    float4 a0 = {0.f, 0.f, 0.f, 0.f};
    float4 a1 = {0.f, 0.f, 0.f, 0.f};
    if (e4 == 0) a0 = *(const float4*)(t + (size_t)c * D + d16 * 4);  // self-loop term

    for (int jb = j0; jb < jend; jb += 64) {
        int m = jend - jb; if (m > 64) m = 64;
        int sv = (jb + lane < jend) ? srcs[jb + lane] : 0;
        int k = 0;
        for (; k + 8 <= m; k += 8) {
            int r0 = __shfl(sv, k + e4);
            int r1 = __shfl(sv, k + 4 + e4);
            float4 v0 = *(const float4*)(t + (size_t)r0 * D + d16 * 4);
            float4 v1 = *(const float4*)(t + (size_t)r1 * D + d16 * 4);
            a0.x += v0.x; a0.y += v0.y; a0.z += v0.z; a0.w += v0.w;
            a1.x += v1.x; a1.y += v1.y; a1.z += v1.z; a1.w += v1.w;
        }
        for (; k < m; k += 4) {
            int idx = k + e4;
            int r = __shfl(sv, idx);
            if (idx < m) {
                float4 v = *(const float4*)(t + (size_t)r * D + d16 * 4);
                a0.x += v.x; a0.y += v.y; a0.z += v.z; a0.w += v.w;
            }
        }
    }
    a0.x += a1.x; a0.y += a1.y; a0.z += a1.z; a0.w += a1.w;
    // reduce across the 4 edge-subgroups (lanes l, l^16, l^32, l^48)
#pragma unroll
    for (int s = 16; s < 64; s <<= 1) {
        a0.x += __shfl_xor(a0.x, s);
        a0.y += __shfl_xor(a0.y, s);
        a0.z += __shfl_xor(a0.z, s);
        a0.w += __shfl_xor(a0.w, s);
    }
    if (e4 == 0) {
        float dsc = dis[c];
        float4 bv = *(const float4*)(b + d16 * 4);
        float4 o;
        o.x = bv.x + dsc * a0.x;
        o.y = bv.y + dsc * a0.y;
        o.z = bv.z + dsc * a0.z;
        o.w = bv.w + dsc * a0.w;
        *(float4*)(out + (size_t)c * D + d16 * 4) = o;
    }
}

// ---------- mid fallback: flat hist/scan/fill CSR ----------

__global__ __launch_bounds__(256) void cnt_init_kernel(int* __restrict__ cnt, int n) {
    int i = blockIdx.x * 256 + threadIdx.x;
    if (i < n) cnt[i] = 0;
}
__global__ __launch_bounds__(256) void hist_kernel(const int* __restrict__ col, int* __restrict__ cnt, int e) {
    int i = blockIdx.x * 256 + threadIdx.x;
    if (i < e) atomicAdd(&cnt[col[i]], 1);
}
__global__ __launch_bounds__(1024) void scan1_kernel(const int* __restrict__ cnt, float* __restrict__ dis,
                                                     int* __restrict__ off, int* __restrict__ bsum, int n) {
    __shared__ int s[1024];
    int tid = threadIdx.x;
    int i = blockIdx.x * 1024 + tid;
    int v = (i < n) ? cnt[i] : 0;
    if (i < n) dis[i] = rsqrtf((float)(v + 1));
    s[tid] = v;
    __syncthreads();
#pragma unroll
    for (int d = 1; d < 1024; d <<= 1) {
        int add = (tid >= d) ? s[tid - d] : 0;
        __syncthreads();
        s[tid] += add;
        __syncthreads();
    }
    int incl = s[tid];
    if (i < n) off[i] = incl - v;
    if (tid == 1023) bsum[blockIdx.x] = incl;
}
__global__ __launch_bounds__(1024) void scan2_kernel(int* __restrict__ bsum, int nb) {
    __shared__ int s[1024];
    int tid = threadIdx.x;
    int v = (tid < nb) ? bsum[tid] : 0;
    s[tid] = v;
    __syncthreads();
#pragma unroll
    for (int d = 1; d < 1024; d <<= 1) {
        int add = (tid >= d) ? s[tid - d] : 0;
        __syncthreads();
        s[tid] += add;
        __syncthreads();
    }
    if (tid < nb) bsum[tid] = s[tid] - v;
}
__global__ __launch_bounds__(1024) void scan3_kernel(int* __restrict__ off, const int* __restrict__ bsum,
                                                     int* __restrict__ cur, int n) {
    int i = blockIdx.x * 1024 + threadIdx.x;
    if (i < n) {
        int o = off[i] + bsum[blockIdx.x];
        off[i] = o;
        cur[i] = o;
    }
}
__global__ __launch_bounds__(256) void fill_kernel(const int* __restrict__ row, const int* __restrict__ col,
                                                   int* __restrict__ cur, int* __restrict__ srcs, int e) {
    int i = blockIdx.x * 256 + threadIdx.x;
    if (i < e) {
        int pos = atomicAdd(&cur[col[i]], 1);
        srcs[pos] = row[i];
    }
}

// ---------- last fallback: atomic scatter ----------

__global__ __launch_bounds__(256) void deg_init_kernel(float* __restrict__ deg, int n) {
    int i = blockIdx.x * 256 + threadIdx.x;
    if (i < n) deg[i] = 1.0f;
}
__global__ __launch_bounds__(256) void deg_count_kernel(const int* __restrict__ col, float* __restrict__ deg, int e) {
    int i = blockIdx.x * 256 + threadIdx.x;
    if (i < e) atomicAdd(&deg[col[i]], 1.0f);
}
__global__ __launch_bounds__(256) void deg_rsqrt_kernel(float* __restrict__ deg, int n) {
    int i = blockIdx.x * 256 + threadIdx.x;
    if (i < n) deg[i] = rsqrtf(deg[i]);
}
__global__ __launch_bounds__(256) void xw_kernel(const float* __restrict__ x, const float* __restrict__ W,
                                                 float* __restrict__ xw, int n) {
    __shared__ float Wl[D * D];
    int tid = threadIdx.x;
    for (int i = tid; i < D * D; i += 256) Wl[i] = W[i];
    __syncthreads();
    int lane = tid & 63;
    int row  = blockIdx.x * 4 + (tid >> 6);
    if (row >= n) return;
    float xv = x[(size_t)row * D + lane];
    float acc = 0.0f;
#pragma unroll
    for (int k = 0; k < D; ++k) acc += __shfl(xv, k) * Wl[k * D + lane];
    xw[(size_t)row * D + lane] = acc;
}
__global__ __launch_bounds__(256) void out_init_kernel(const float* __restrict__ xw, const float* __restrict__ dis,
                                                       const float* __restrict__ b, float* __restrict__ out, int n) {
    int i = blockIdx.x * 256 + threadIdx.x;
    if (i < n * D) {
        int node = i >> 6;
        float d = dis[node];
        out[i] = b[i & 63] + d * d * xw[i];
    }
}
__global__ __launch_bounds__(256) void scatter_kernel(const int* __restrict__ row, const int* __restrict__ col,
                                                      const float* __restrict__ dis, const float* __restrict__ xw,
                                                      float* __restrict__ out, int e) {
    int idx  = blockIdx.x * 4 + (threadIdx.x >> 6);
    int lane = threadIdx.x & 63;
    if (idx >= e) return;
    int r = row[idx], c = col[idx];
    float w = dis[r] * dis[c];
    atomicAdd(&out[(size_t)c * D + lane], w * xw[(size_t)r * D + lane]);
}

// ---------- launch ----------

extern "C" void kernel_launch(void* const* d_in, const int* in_sizes, int n_in,
                              void* d_out, int out_size, void* d_ws, size_t ws_size,
                              hipStream_t stream) {
    const float* x  = (const float*)d_in[0];
    const int*   ei = (const int*)d_in[1];
    const float* W  = (const float*)d_in[2];
    const float* b  = (const float*)d_in[3];
    float*       out = (float*)d_out;

    int n = in_sizes[0] / D;   // 100000
    int e = in_sizes[1] / 2;   // 1600000
    const int* row = ei;
    const int* col = ei + e;

    size_t nA = ((size_t)n + 255) & ~(size_t)255;
    int nb = (n + BCOLS - 1) >> BSH;

    size_t fast_needed = (size_t)(1024 + 1056 + 1024) * 4 + (2 * nA) * 4 + (nA + nA * D) * 4 + 2 * (size_t)e * 4;
    size_t mid_needed  = (3 * nA + 1024) * 4 + (nA + nA * D) * 4 + (size_t)e * 4;

    if (n <= 131072 && nb <= MAXNB && ws_size >= fast_needed) {
        int*   bcnt   = (int*)d_ws;
        int*   base   = bcnt + 1024;
        int*   bcur   = base + 1056;
        int*   off    = bcur + 1024;
        int*   end    = off + nA;
        float* dis    = (float*)(end + nA);
        float* t      = dis + nA;
        unsigned int* binned = (unsigned int*)(t + nA * D);
        int*   srcs   = (int*)(binned + e);

        int chunk = (e + NBLK3 - 1) / NBLK3;

        zinit_kernel<<<(nb + 255) / 256, 256, 0, stream>>>(bcnt, nb);
        bhist_kernel<<<256, 256, 0, stream>>>(col, bcnt, e, nb);
        bscan_kernel<<<1, 1024, 0, stream>>>(bcnt, base, bcur, nb, e);
        bscatter_kernel<<<NBLK3, 256, 0, stream>>>(row, col, bcur, binned, e, nb, chunk);
        bucket_build_kernel<<<nb, 256, 0, stream>>>(base, binned, off, end, dis, srcs, n);
        xw_t_gemm_kernel<<<(n + BM - 1) / BM, 256, 0, stream>>>(x, W, dis, t, n);
        gather4_kernel<<<(n + 3) / 4, 256, 0, stream>>>(off, end, srcs, t, dis, b, out, n);
    } else if (ws_size >= mid_needed) {
        int*   cnt  = (int*)d_ws;
        int*   off  = cnt + nA;
        int*   cur  = off + nA;
        int*   bsum = cur + nA;
        float* dis  = (float*)(bsum + 1024);
        float* t    = dis + nA;
        int*   srcs = (int*)(t + nA * D);

        int nblk = (n + 1023) / 1024;
        cnt_init_kernel<<<(n + 255) / 256, 256, 0, stream>>>(cnt, n);
        hist_kernel<<<(e + 255) / 256, 256, 0, stream>>>(col, cnt, e);
        scan1_kernel<<<nblk, 1024, 0, stream>>>(cnt, dis, off, bsum, n);
        scan2_kernel<<<1, 1024, 0, stream>>>(bsum, nblk);
        scan3_kernel<<<nblk, 1024, 0, stream>>>(off, bsum, cur, n);
        xw_t_gemm_kernel<<<(n + BM - 1) / BM, 256, 0, stream>>>(x, W, dis, t, n);
        fill_kernel<<<(e + 255) / 256, 256, 0, stream>>>(row, col, cur, srcs, e);
        gather4_kernel<<<(n + 3) / 4, 256, 0, stream>>>(off, cur, srcs, t, dis, b, out, n);
    } else {
        float* deg = (float*)d_ws;
        float* xw  = deg + nA;
        deg_init_kernel<<<(n + 255) / 256, 256, 0, stream>>>(deg, n);
        deg_count_kernel<<<(e + 255) / 256, 256, 0, stream>>>(col, deg, e);
        deg_rsqrt_kernel<<<(n + 255) / 256, 256, 0, stream>>>(deg, n);
        xw_kernel<<<(n + 3) / 4, 256, 0, stream>>>(x, W, xw, n);
        out_init_kernel<<<((size_t)n * D + 255) / 256, 256, 0, stream>>>(xw, deg, b, out, n);
        scatter_kernel<<<(e + 3) / 4, 256, 0, stream>>>(row, col, deg, xw, out, e);
    }
}

// Round 6
// 128.953 us; speedup vs baseline: 4.2877x; 1.1262x over previous
//
#include <hip/hip_runtime.h>

// GCNConv forward via bucketed on-device CSR build + bf16 register gather.
// t[i] = bf16( dis[i]*(x@W)[i] );  out[c] = b + dis[c]*( t[c] + sum_{edges r->c} t[r] )

#define D 64
#define BSH 7            // bucket shift: 128 cols per bucket
#define BCOLS 128
#define MAXNB 1024       // supports n <= 131072 (row fits in 20 bits)
#define BM 128           // GEMM rows per block
#define NBLK3 512        // bscatter blocks

__device__ inline unsigned short f2bf(float f) {   // RNE fp32 -> bf16
    unsigned u = __float_as_uint(f);
    return (unsigned short)((u + 0x7FFFu + ((u >> 16) & 1u)) >> 16);
}

// ---------- fast path: bucketed CSR build ----------

__global__ __launch_bounds__(256) void bhist_kernel(const int* __restrict__ col, int* __restrict__ bcnt,
                                                    int e, int nb) {
    __shared__ int h[MAXNB];
    int tid = threadIdx.x;
    for (int i = tid; i < nb; i += 256) h[i] = 0;
    __syncthreads();
    int stride = gridDim.x * 256;
    for (int i = blockIdx.x * 256 + tid; i < e; i += stride)
        atomicAdd(&h[col[i] >> BSH], 1);
    __syncthreads();
    for (int i = tid; i < nb; i += 256)
        if (h[i]) atomicAdd(&bcnt[i], h[i]);
}

__global__ __launch_bounds__(1024) void bscan_kernel(const int* __restrict__ bcnt, int* __restrict__ base,
                                                     int* __restrict__ cur, int nb, int e) {
    __shared__ int s[1024];
    int tid = threadIdx.x;
    int v = (tid < nb) ? bcnt[tid] : 0;
    s[tid] = v;
    __syncthreads();
#pragma unroll
    for (int d = 1; d < 1024; d <<= 1) {
        int add = (tid >= d) ? s[tid - d] : 0;
        __syncthreads();
        s[tid] += add;
        __syncthreads();
    }
    if (tid < nb) { int ex = s[tid] - v; base[tid] = ex; cur[tid] = ex; }
    if (tid == 0) base[nb] = e;
}

// Bucket-grouped packed edges: binned[pos] = ((col&127) << 20) | row
__global__ __launch_bounds__(256) void bscatter_kernel(const int* __restrict__ row, const int* __restrict__ col,
                                                       int* __restrict__ bcur, unsigned int* __restrict__ binned,
                                                       int e, int nb, int chunk) {
    __shared__ int h[MAXNB];
    __shared__ int res[MAXNB];
    int tid = threadIdx.x;
    for (int i = tid; i < nb; i += 256) h[i] = 0;
    __syncthreads();
    int i0 = blockIdx.x * chunk;
    int i1 = i0 + chunk; if (i1 > e) i1 = e;
    for (int i = i0 + tid; i < i1; i += 256)
        atomicAdd(&h[col[i] >> BSH], 1);
    __syncthreads();
    for (int b = tid; b < nb; b += 256) {
        int c = h[b];
        res[b] = c ? atomicAdd(&bcur[b], c) : 0;
        h[b] = 0;  // reuse as local cursor
    }
    __syncthreads();
    for (int i = i0 + tid; i < i1; i += 256) {
        int cl = col[i];
        int b = cl >> BSH;
        int pos = res[b] + atomicAdd(&h[b], 1);
        binned[pos] = ((unsigned int)(cl & (BCOLS - 1)) << 20) | (unsigned int)row[i];
    }
}

__global__ __launch_bounds__(256) void bucket_build_kernel(const int* __restrict__ base,
                                                           const unsigned int* __restrict__ binned,
                                                           int* __restrict__ off, int* __restrict__ end,
                                                           float* __restrict__ dis, int* __restrict__ srcs,
                                                           int n) {
    __shared__ int hc[BCOLS];
    __shared__ int ho[BCOLS];
    __shared__ int hcur[BCOLS];
    int tid = threadIdx.x;
    int b = blockIdx.x;
    int s0 = base[b], s1 = base[b + 1];
    if (tid < BCOLS) hc[tid] = 0;
    __syncthreads();
    for (int i = s0 + tid; i < s1; i += 256)
        atomicAdd(&hc[binned[i] >> 20], 1);
    __syncthreads();
    if (tid < BCOLS) ho[tid] = hc[tid];
    __syncthreads();
#pragma unroll
    for (int d = 1; d < BCOLS; d <<= 1) {
        int add = (tid < BCOLS && tid >= d) ? ho[tid - d] : 0;
        __syncthreads();
        if (tid < BCOLS) ho[tid] += add;
        __syncthreads();
    }
    if (tid < BCOLS) {
        int col = (b << BSH) + tid;
        if (col < n) {
            int ex = ho[tid] - hc[tid];
            off[col] = s0 + ex;
            end[col] = s0 + ho[tid];
            dis[col] = rsqrtf((float)(hc[tid] + 1));  // +1 self loop
            hcur[tid] = s0 + ex;
        }
    }
    __syncthreads();
    for (int i = s0 + tid; i < s1; i += 256) {
        unsigned int v = binned[i];
        int lc = v >> 20;
        int pos = atomicAdd(&hcur[lc], 1);
        srcs[pos] = (int)(v & 0xFFFFFu);
    }
}

// ---------- t = bf16( dis * (x @ W) ): register-tiled fp32 GEMM ----------

__global__ __launch_bounds__(256) void xw_t_gemm_kernel(const float* __restrict__ x, const float* __restrict__ W,
                                                        const float* __restrict__ dis,
                                                        unsigned short* __restrict__ t, int n) {
    __shared__ float xT[D][BM];   // [k][row], 32 KB
    __shared__ float Wl[D][D];    // [k][col], 16 KB
    int tid = threadIdx.x;
    int r0 = blockIdx.x * BM;

    {
        const float4* Wv = (const float4*)W;
        float4* Wd = (float4*)&Wl[0][0];
#pragma unroll
        for (int j = 0; j < 4; ++j) Wd[j * 256 + tid] = Wv[j * 256 + tid];
    }
    {
        int row = tid >> 1;
        int c0 = (tid & 1) * 32;
        int gr = r0 + row;
        if (gr < n) {
            const float4* xv = (const float4*)(x + (size_t)gr * D + c0);
#pragma unroll
            for (int j = 0; j < 8; ++j) {
                float4 v = xv[j];
                int c = c0 + j * 4;
                xT[c + 0][row] = v.x;
                xT[c + 1][row] = v.y;
                xT[c + 2][row] = v.z;
                xT[c + 3][row] = v.w;
            }
        }
    }
    __syncthreads();

    int cg = tid & 15;
    int rg = tid >> 4;
    float acc[8][4];
#pragma unroll
    for (int i = 0; i < 8; ++i)
#pragma unroll
        for (int j = 0; j < 4; ++j) acc[i][j] = 0.0f;

#pragma unroll 8
    for (int k = 0; k < D; ++k) {
        float4 xa = *(const float4*)&xT[k][rg * 8];
        float4 xb = *(const float4*)&xT[k][rg * 8 + 4];
        float4 wv = *(const float4*)&Wl[k][cg * 4];
        float xr[8] = {xa.x, xa.y, xa.z, xa.w, xb.x, xb.y, xb.z, xb.w};
        float wr[4] = {wv.x, wv.y, wv.z, wv.w};
#pragma unroll
        for (int i = 0; i < 8; ++i)
#pragma unroll
            for (int j = 0; j < 4; ++j) acc[i][j] += xr[i] * wr[j];
    }

#pragma unroll
    for (int i = 0; i < 8; ++i) {
        int gr = r0 + rg * 8 + i;
        if (gr < n) {
            float dsc = dis[gr];
            ushort4 o;
            o.x = f2bf(acc[i][0] * dsc); o.y = f2bf(acc[i][1] * dsc);
            o.z = f2bf(acc[i][2] * dsc); o.w = f2bf(acc[i][3] * dsc);
            *(ushort4*)(t + (size_t)gr * D + cg * 4) = o;
        }
    }
}

// ---------- gather: one wave per node, 8-edge subgroups, bf16 rows ----------
// lane = e8*8 + d8: subgroup e8 handles edge (k+e8); d8 covers 8 bf16 (16B) of the 128B row.

__device__ inline void add8(float* acc, uint4 u) {
    unsigned w0 = u.x, w1 = u.y, w2 = u.z, w3 = u.w;
    acc[0] += __uint_as_float(w0 << 16);
    acc[1] += __uint_as_float(w0 & 0xFFFF0000u);
    acc[2] += __uint_as_float(w1 << 16);
    acc[3] += __uint_as_float(w1 & 0xFFFF0000u);
    acc[4] += __uint_as_float(w2 << 16);
    acc[5] += __uint_as_float(w2 & 0xFFFF0000u);
    acc[6] += __uint_as_float(w3 << 16);
    acc[7] += __uint_as_float(w3 & 0xFFFF0000u);
}

__global__ __launch_bounds__(256) void gather8_kernel(const int* __restrict__ off, const int* __restrict__ end,
                                                      const int* __restrict__ srcs,
                                                      const unsigned short* __restrict__ t,
                                                      const float* __restrict__ dis, const float* __restrict__ b,
                                                      float* __restrict__ out, int n) {
    int c    = blockIdx.x * 4 + (threadIdx.x >> 6);
    int lane = threadIdx.x & 63;
    if (c >= n) return;
    int e8 = lane >> 3;   // edge subgroup 0..7
    int d8 = lane & 7;    // 16B chunk of row
    int j0 = off[c];
    int jend = end[c];

    float acc[8];
#pragma unroll
    for (int q = 0; q < 8; ++q) acc[q] = 0.0f;

    if (e8 == 0) {  // self-loop term
        uint4 u = *(const uint4*)(t + (size_t)c * D + d8 * 8);
        add8(acc, u);
    }

    for (int jb = j0; jb < jend; jb += 64) {
        int m = jend - jb; if (m > 64) m = 64;
        int sv = (jb + lane < jend) ? srcs[jb + lane] : 0;
        int k = 0;
        for (; k + 16 <= m; k += 16) {
            int r0 = __shfl(sv, k + e8);
            int r1 = __shfl(sv, k + 8 + e8);
            uint4 u0 = *(const uint4*)(t + (size_t)r0 * D + d8 * 8);
            uint4 u1 = *(const uint4*)(t + (size_t)r1 * D + d8 * 8);
            add8(acc, u0);
            add8(acc, u1);
        }
        for (; k < m; k += 8) {
            int idx = k + e8;
            int r = __shfl(sv, idx);
            if (idx < m) {
                uint4 u = *(const uint4*)(t + (size_t)r * D + d8 * 8);
                add8(acc, u);
            }
        }
    }

    // reduce across the 8 edge-subgroups (xor 8,16,32)
#pragma unroll
    for (int s = 8; s < 64; s <<= 1)
#pragma unroll
        for (int q = 0; q < 8; ++q) acc[q] += __shfl_xor(acc[q], s);

    if (e8 == 0) {
        float dsc = dis[c];
        float* op = out + (size_t)c * D + d8 * 8;
        const float* bp = b + d8 * 8;
        float4 o0, o1;
        o0.x = bp[0] + dsc * acc[0]; o0.y = bp[1] + dsc * acc[1];
        o0.z = bp[2] + dsc * acc[2]; o0.w = bp[3] + dsc * acc[3];
        o1.x = bp[4] + dsc * acc[4]; o1.y = bp[5] + dsc * acc[5];
        o1.z = bp[6] + dsc * acc[6]; o1.w = bp[7] + dsc * acc[7];
        *(float4*)op = o0;
        *(float4*)(op + 4) = o1;
    }
}

// ---------- mid fallback: flat hist/scan/fill CSR ----------

__global__ __launch_bounds__(256) void cnt_init_kernel(int* __restrict__ cnt, int n) {
    int i = blockIdx.x * 256 + threadIdx.x;
    if (i < n) cnt[i] = 0;
}
__global__ __launch_bounds__(256) void hist_kernel(const int* __restrict__ col, int* __restrict__ cnt, int e) {
    int i = blockIdx.x * 256 + threadIdx.x;
    if (i < e) atomicAdd(&cnt[col[i]], 1);
}
__global__ __launch_bounds__(1024) void scan1_kernel(const int* __restrict__ cnt, float* __restrict__ dis,
                                                     int* __restrict__ off, int* __restrict__ bsum, int n) {
    __shared__ int s[1024];
    int tid = threadIdx.x;
    int i = blockIdx.x * 1024 + tid;
    int v = (i < n) ? cnt[i] : 0;
    if (i < n) dis[i] = rsqrtf((float)(v + 1));
    s[tid] = v;
    __syncthreads();
#pragma unroll
    for (int d = 1; d < 1024; d <<= 1) {
        int add = (tid >= d) ? s[tid - d] : 0;
        __syncthreads();
        s[tid] += add;
        __syncthreads();
    }
    int incl = s[tid];
    if (i < n) off[i] = incl - v;
    if (tid == 1023) bsum[blockIdx.x] = incl;
}
__global__ __launch_bounds__(1024) void scan2_kernel(int* __restrict__ bsum, int nb) {
    __shared__ int s[1024];
    int tid = threadIdx.x;
    int v = (tid < nb) ? bsum[tid] : 0;
    s[tid] = v;
    __syncthreads();
#pragma unroll
    for (int d = 1; d < 1024; d <<= 1) {
        int add = (tid >= d) ? s[tid - d] : 0;
        __syncthreads();
        s[tid] += add;
        __syncthreads();
    }
    if (tid < nb) bsum[tid] = s[tid] - v;
}
__global__ __launch_bounds__(1024) void scan3_kernel(int* __restrict__ off, const int* __restrict__ bsum,
                                                     int* __restrict__ cur, int n) {
    int i = blockIdx.x * 1024 + threadIdx.x;
    if (i < n) {
        int o = off[i] + bsum[blockIdx.x];
        off[i] = o;
        cur[i] = o;
    }
}
__global__ __launch_bounds__(256) void fill_kernel(const int* __restrict__ row, const int* __restrict__ col,
                                                   int* __restrict__ cur, int* __restrict__ srcs, int e) {
    int i = blockIdx.x * 256 + threadIdx.x;
    if (i < e) {
        int pos = atomicAdd(&cur[col[i]], 1);
        srcs[pos] = row[i];
    }
}

// ---------- last fallback: atomic scatter (fp32 throughout) ----------

__global__ __launch_bounds__(256) void deg_init_kernel(float* __restrict__ deg, int n) {
    int i = blockIdx.x * 256 + threadIdx.x;
    if (i < n) deg[i] = 1.0f;
}
__global__ __launch_bounds__(256) void deg_count_kernel(const int* __restrict__ col, float* __restrict__ deg, int e) {
    int i = blockIdx.x * 256 + threadIdx.x;
    if (i < e) atomicAdd(&deg[col[i]], 1.0f);
}
__global__ __launch_bounds__(256) void deg_rsqrt_kernel(float* __restrict__ deg, int n) {
    int i = blockIdx.x * 256 + threadIdx.x;
    if (i < n) deg[i] = rsqrtf(deg[i]);
}
__global__ __launch_bounds__(256) void xw_kernel(const float* __restrict__ x, const float* __restrict__ W,
                                                 float* __restrict__ xw, int n) {
    __shared__ float Wl[D * D];
    int tid = threadIdx.x;
    for (int i = tid; i < D * D; i += 256) Wl[i] = W[i];
    __syncthreads();
    int lane = tid & 63;
    int row  = blockIdx.x * 4 + (tid >> 6);
    if (row >= n) return;
    float xv = x[(size_t)row * D + lane];
    float acc = 0.0f;
#pragma unroll
    for (int k = 0; k < D; ++k) acc += __shfl(xv, k) * Wl[k * D + lane];
    xw[(size_t)row * D + lane] = acc;
}
__global__ __launch_bounds__(256) void out_init_kernel(const float* __restrict__ xw, const float* __restrict__ dis,
                                                       const float* __restrict__ b, float* __restrict__ out, int n) {
    int i = blockIdx.x * 256 + threadIdx.x;
    if (i < n * D) {
        int node = i >> 6;
        float d = dis[node];
        out[i] = b[i & 63] + d * d * xw[i];
    }
}
__global__ __launch_bounds__(256) void scatter_kernel(const int* __restrict__ row, const int* __restrict__ col,
                                                      const float* __restrict__ dis, const float* __restrict__ xw,
                                                      float* __restrict__ out, int e) {
    int idx  = blockIdx.x * 4 + (threadIdx.x >> 6);
    int lane = threadIdx.x & 63;
    if (idx >= e) return;
    int r = row[idx], c = col[idx];
    float w = dis[r] * dis[c];
    atomicAdd(&out[(size_t)c * D + lane], w * xw[(size_t)r * D + lane]);
}

// ---------- launch ----------

extern "C" void kernel_launch(void* const* d_in, const int* in_sizes, int n_in,
                              void* d_out, int out_size, void* d_ws, size_t ws_size,
                              hipStream_t stream) {
    const float* x  = (const float*)d_in[0];
    const int*   ei = (const int*)d_in[1];
    const float* W  = (const float*)d_in[2];
    const float* b  = (const float*)d_in[3];
    float*       out = (float*)d_out;

    int n = in_sizes[0] / D;   // 100000
    int e = in_sizes[1] / 2;   // 1600000
    const int* row = ei;
    const int* col = ei + e;

    size_t nA = ((size_t)n + 255) & ~(size_t)255;
    int nb = (n + BCOLS - 1) >> BSH;

    // fast: bcnt[1024] base[1056] bcur[1024] off[nA] end[nA] (int) | dis[nA] (f32) | t[nA*D] (bf16) | binned[e] srcs[e]
    size_t fast_needed = (size_t)(1024 + 1056 + 1024) * 4 + 2 * nA * 4 + nA * 4 + nA * D * 2 + 2 * (size_t)e * 4;
    size_t mid_needed  = (3 * nA + 1024) * 4 + nA * 4 + nA * D * 2 + (size_t)e * 4;

    if (n <= 131072 && nb <= MAXNB && ws_size >= fast_needed) {
        int*   bcnt   = (int*)d_ws;
        int*   base   = bcnt + 1024;
        int*   bcur   = base + 1056;
        int*   off    = bcur + 1024;
        int*   end    = off + nA;
        float* dis    = (float*)(end + nA);
        unsigned short* t = (unsigned short*)(dis + nA);
        unsigned int* binned = (unsigned int*)(t + nA * D);
        int*   srcs   = (int*)(binned + e);

        int chunk = (e + NBLK3 - 1) / NBLK3;

        hipMemsetAsync(bcnt, 0, (size_t)nb * 4, stream);
        bhist_kernel<<<256, 256, 0, stream>>>(col, bcnt, e, nb);
        bscan_kernel<<<1, 1024, 0, stream>>>(bcnt, base, bcur, nb, e);
        bscatter_kernel<<<NBLK3, 256, 0, stream>>>(row, col, bcur, binned, e, nb, chunk);
        bucket_build_kernel<<<nb, 256, 0, stream>>>(base, binned, off, end, dis, srcs, n);
        xw_t_gemm_kernel<<<(n + BM - 1) / BM, 256, 0, stream>>>(x, W, dis, t, n);
        gather8_kernel<<<(n + 3) / 4, 256, 0, stream>>>(off, end, srcs, t, dis, b, out, n);
    } else if (ws_size >= mid_needed) {
        int*   cnt  = (int*)d_ws;
        int*   off  = cnt + nA;
        int*   cur  = off + nA;
        int*   bsum = cur + nA;
        float* dis  = (float*)(bsum + 1024);
        unsigned short* t = (unsigned short*)(dis + nA);
        int*   srcs = (int*)(t + nA * D);

        int nblk = (n + 1023) / 1024;
        cnt_init_kernel<<<(n + 255) / 256, 256, 0, stream>>>(cnt, n);
        hist_kernel<<<(e + 255) / 256, 256, 0, stream>>>(col, cnt, e);
        scan1_kernel<<<nblk, 1024, 0, stream>>>(cnt, dis, off, bsum, n);
        scan2_kernel<<<1, 1024, 0, stream>>>(bsum, nblk);
        scan3_kernel<<<nblk, 1024, 0, stream>>>(off, bsum, cur, n);
        xw_t_gemm_kernel<<<(n + BM - 1) / BM, 256, 0, stream>>>(x, W, dis, t, n);
        fill_kernel<<<(e + 255) / 256, 256, 0, stream>>>(row, col, cur, srcs, e);
        gather8_kernel<<<(n + 3) / 4, 256, 0, stream>>>(off, cur, srcs, t, dis, b, out, n);
    } else {
        float* deg = (float*)d_ws;
        float* xw  = deg + nA;
        deg_init_kernel<<<(n + 255) / 256, 256, 0, stream>>>(deg, n);
        deg_count_kernel<<<(e + 255) / 256, 256, 0, stream>>>(col, deg, e);
        deg_rsqrt_kernel<<<(n + 255) / 256, 256, 0, stream>>>(deg, n);
        xw_kernel<<<(n + 3) / 4, 256, 0, stream>>>(x, W, xw, n);
        out_init_kernel<<<((size_t)n * D + 255) / 256, 256, 0, stream>>>(xw, deg, b, out, n);
        scatter_kernel<<<(e + 3) / 4, 256, 0, stream>>>(row, col, deg, xw, out, e);
    }
}